// Round 4
// baseline (178.788 us; speedup 1.0000x reference)
//
#include <hip/hip_runtime.h>
#include <hip/hip_cooperative_groups.h>

namespace cg = cooperative_groups;

typedef float f4 __attribute__((ext_vector_type(4)));
typedef short bf16x8 __attribute__((ext_vector_type(8)));
typedef float f32x4 __attribute__((ext_vector_type(4)));

#define BB 32
#define CC 64
#define EE 8
#define HWX 4096   // 64*64 pixels
#define PXT 128    // pixels per block tile (2 image rows)
#define SX 132     // LDS row stride for x tile (f4-aligned, breaks some aliasing)

// ---------------------------------------------------------------------------
// bf16 round-to-nearest-even helpers
// ---------------------------------------------------------------------------
__device__ __forceinline__ unsigned bf16r(float f) {
  unsigned u = __builtin_bit_cast(unsigned, f);
  u += 0x7FFFu + ((u >> 16) & 1u);
  return u >> 16;
}
__device__ __forceinline__ unsigned pack2(float a, float b) {
  return bf16r(a) | (bf16r(b) << 16);
}
union frag_cast { bf16x8 v; unsigned u[4]; };

// ---------------------------------------------------------------------------
// Fused cooperative kernel.
// Block (pt,b): owns image rows {2pt, 2pt+1} of all 64 channels of batch b
// (128 px x 64 ch = 32 KB tile in LDS, staged ONCE).
// Phase 1: tile's linear contribution to gating logits -> gcontrib[b][pt][e].
//   gating[b,e] = sum_c sum_{ij} gw[e,c,i,j]*S_c[i,j],
//   S = T - exclRows(i) - exclCols(j) + corners(i,j)  (all linear in tiles).
// grid.sync()
// Phase 2: reduce gcontrib (bit-identical in all blocks of b), softmax/top-1,
// MFMA 1x1-conv mix using the LDS-resident tile (x read from HBM exactly once).
// ---------------------------------------------------------------------------
__global__ __launch_bounds__(256, 4) void k_fused(
    const float* __restrict__ x, const float* __restrict__ gate_w,
    const float* __restrict__ gate_b, const float* __restrict__ expert_w,
    float* __restrict__ out, float* __restrict__ ew_out,
    float* __restrict__ gcontrib) {
  __shared__ __align__(16) float xt[CC * SX];  // 33792 B
  __shared__ float pT[CC];        // tile totals per channel
  __shared__ float rp4[CC][4];    // row sums for rows {0,1,62,63} (edge tiles)
  __shared__ float cA[CC][4];     // row-A values at cols {0,1,62,63}
  __shared__ float cB[CC][4];     // row-B values at cols {0,1,62,63}
  __shared__ float gsh[EE];

  int t = threadIdx.x;
  int blk = blockIdx.x;
  int b = blk >> 5, pt = blk & 31;
  const float* Xg = x + (size_t)b * CC * HWX + pt * PXT;

  ((float*)rp4)[t] = 0.f;

  // ---- stage tile: thread t -> px group g (16B), channels u+8k ----
  int g = t & 31, u = t >> 5;
  f4 v[8];
  #pragma unroll
  for (int k = 0; k < 8; k++) {
    int c = u + 8 * k;
    v[k] = *(const f4*)(Xg + (size_t)c * HWX + 4 * g);
    *(f4*)&xt[c * SX + 4 * g] = v[k];
  }
  __syncthreads();   // rp4 zeros + xt visible

  // ---- per-channel tile stats (groups of 32 lanes share a channel set) ----
  #pragma unroll
  for (int k = 0; k < 8; k++) {
    int c = u + 8 * k;
    float s = v[k][0] + v[k][1] + v[k][2] + v[k][3];
    s += __shfl_down(s, 8, 16);
    s += __shfl_down(s, 4, 16);
    s += __shfl_down(s, 2, 16);
    s += __shfl_down(s, 1, 16);       // lanes g==0: rowA sum, g==16: rowB sum
    float sB = __shfl_down(s, 16, 32);
    if (g == 0) {
      pT[c] = s + sB;
      if (pt == 0)  { rp4[c][0] = s; rp4[c][1] = sB; }
      if (pt == 31) { rp4[c][2] = s; rp4[c][3] = sB; }
      cA[c][0] = v[k][0]; cA[c][1] = v[k][1];     // cols 0,1 row A
    }
    if (g == 15) { cA[c][2] = v[k][2]; cA[c][3] = v[k][3]; }  // cols 62,63 A
    if (g == 16) { cB[c][0] = v[k][0]; cB[c][1] = v[k][1]; }  // cols 0,1  B
    if (g == 31) { cB[c][2] = v[k][2]; cB[c][3] = v[k][3]; }  // cols 62,63 B
  }
  __syncthreads();

  // ---- gating contribution: 512 (e,c) tasks over 2 halves ----
  bool ed0 = (pt == 0), ed31 = (pt == 31);
  float contrib0 = 0.f, contrib1 = 0.f;
  #pragma unroll
  for (int half = 0; half < 2; half++) {
    int task = t + 256 * half;
    int e = task >> 6, c = task & 63;
    float T = pT[c];
    float rs[4] = {rp4[c][0], rp4[c][1], rp4[c][2], rp4[c][3]};
    float a0 = cA[c][0], a1 = cA[c][1], a2 = cA[c][2], a3 = cA[c][3];
    float b0 = cB[c][0], b1 = cB[c][1], b2 = cB[c][2], b3 = cB[c][3];
    float cs[4] = {a0 + b0, a1 + b1, a2 + b2, a3 + b3};
    float crn[4][4];
    #pragma unroll
    for (int ri = 0; ri < 4; ri++)
      #pragma unroll
      for (int j = 0; j < 4; j++) crn[ri][j] = 0.f;
    if (ed0)  { crn[0][0]=a0; crn[0][1]=a1; crn[0][2]=a2; crn[0][3]=a3;
                crn[1][0]=b0; crn[1][1]=b1; crn[1][2]=b2; crn[1][3]=b3; }
    if (ed31) { crn[2][0]=a0; crn[2][1]=a1; crn[2][2]=a2; crn[2][3]=a3;
                crn[3][0]=b0; crn[3][1]=b1; crn[3][2]=b2; crn[3][3]=b3; }
    const int EX[3][2] = {{2,3},{0,3},{0,1}};
    const float* gw = gate_w + (size_t)(e * CC + c) * 9;
    float acc = 0.f;
    #pragma unroll
    for (int i = 0; i < 3; i++)
      #pragma unroll
      for (int j = 0; j < 3; j++) {
        float Re = rs[EX[i][0]] + rs[EX[i][1]];
        float Ce = cs[EX[j][0]] + cs[EX[j][1]];
        float Xc = crn[EX[i][0]][EX[j][0]] + crn[EX[i][0]][EX[j][1]]
                 + crn[EX[i][1]][EX[j][0]] + crn[EX[i][1]][EX[j][1]];
        acc += gw[i * 3 + j] * (T - Re - Ce + Xc);
      }
    if (half == 0) contrib0 = acc; else contrib1 = acc;
  }
  #pragma unroll
  for (int off = 32; off; off >>= 1) {
    contrib0 += __shfl_down(contrib0, off, 64);
    contrib1 += __shfl_down(contrib1, off, 64);
  }
  int lane = t & 63, wv = t >> 6;
  if (lane == 0) {
    float* gc = gcontrib + ((size_t)(b * 32 + pt)) * EE;
    gc[wv] = contrib0;        // expert wv
    gc[wv + 4] = contrib1;    // expert wv+4
  }

  cg::this_grid().sync();

  // ---- gating reduce (wave 0; deterministic, identical in all blocks of b) ----
  if (t < 64) {
    int e = t & 7, ch = t >> 3;
    const float* gc = gcontrib + (size_t)b * 256;
    float p = gc[(ch * 4 + 0) * 8 + e] + gc[(ch * 4 + 1) * 8 + e]
            + gc[(ch * 4 + 2) * 8 + e] + gc[(ch * 4 + 3) * 8 + e];
    p += __shfl_down(p, 32, 64);
    p += __shfl_down(p, 16, 64);
    p += __shfl_down(p, 8, 64);
    if (t < 8) gsh[t] = p + 3844.0f * gate_b[t];
  }
  __syncthreads();

  // ---- softmax / top-1 (block-uniform) ----
  float gg[EE];
  #pragma unroll
  for (int e = 0; e < EE; e++) gg[e] = gsh[e];
  int best = 0; float bg = gg[0];
  #pragma unroll
  for (int e = 1; e < EE; e++) if (gg[e] > bg) { bg = gg[e]; best = e; }
  float s = 0.f;
  #pragma unroll
  for (int e = 0; e < EE; e++) s += __expf(gg[e] - bg);
  float sc = 1.0f / s;
  if (pt == 0 && t < EE) ew_out[b * EE + t] = (t == best) ? sc : 0.f;

  // ---- MFMA mix from the LDS-resident tile ----
  int l15 = lane & 15, quad = lane >> 4;
  const float* Wg = expert_w + (size_t)best * (CC * CC);
  bf16x8 afr[4][2];
  #pragma unroll
  for (int ft = 0; ft < 4; ft++) {
    const float* wrow = Wg + (ft * 16 + l15) * CC + quad * 8;
    #pragma unroll
    for (int kk = 0; kk < 2; kk++) {
      f4 w0 = *(const f4*)(wrow + kk * 32);
      f4 w1 = *(const f4*)(wrow + kk * 32 + 4);
      frag_cast fc;
      fc.u[0] = pack2(w0[0], w0[1]); fc.u[1] = pack2(w0[2], w0[3]);
      fc.u[2] = pack2(w1[0], w1[1]); fc.u[3] = pack2(w1[2], w1[3]);
      afr[ft][kk] = fc.v;
    }
  }

  f32x4 acc2[2][4] = {};
  #pragma unroll
  for (int ss = 0; ss < 2; ss++) {
    int pxl = 32 * wv + 16 * ss + l15;
    #pragma unroll
    for (int kk = 0; kk < 2; kk++) {
      int k0 = kk * 32 + quad * 8;
      const float* xr = &xt[k0 * SX + pxl];
      frag_cast fb;
      fb.u[0] = pack2(xr[0],      xr[SX]);
      fb.u[1] = pack2(xr[2 * SX], xr[3 * SX]);
      fb.u[2] = pack2(xr[4 * SX], xr[5 * SX]);
      fb.u[3] = pack2(xr[6 * SX], xr[7 * SX]);
      #pragma unroll
      for (int ft = 0; ft < 4; ft++)
        acc2[ss][ft] = __builtin_amdgcn_mfma_f32_16x16x32_bf16(
            afr[ft][kk], fb.v, acc2[ss][ft], 0, 0, 0);
    }
  }

  #pragma unroll
  for (int ss = 0; ss < 2; ss++)
    #pragma unroll
    for (int ft = 0; ft < 4; ft++) {
      int f = ft * 16 + quad * 4;
      float* Og = out + ((size_t)(b * CC + f)) * HWX
                + pt * PXT + 32 * wv + ss * 16 + l15;
      #pragma unroll
      for (int r = 0; r < 4; r++)
        Og[(size_t)r * HWX] = sc * acc2[ss][ft][r];
    }
}

// ===========================================================================
// Fallback path (R3, verified): used only if cooperative launch is refused.
// ===========================================================================
__global__ __launch_bounds__(256) void k_gate_sums(
    const float* __restrict__ x, const float* __restrict__ gate_w,
    float* __restrict__ gpart) {
  __shared__ float sg[9];
  __shared__ float cor[4][4];
  __shared__ float sS[9];
  int t = threadIdx.x;
  int bc = blockIdx.x;
  int c = bc & 63;
  const float* plane = x + (size_t)bc * HWX;
  int h = t >> 2, q = t & 3;
  const f4* rp = (const f4*)(plane + h * 64 + q * 16);
  f4 a0 = rp[0], a1 = rp[1], a2 = rp[2], a3 = rp[3];
  float local = (a0[0]+a0[1]+a0[2]+a0[3]) + (a1[0]+a1[1]+a1[2]+a1[3])
              + (a2[0]+a2[1]+a2[2]+a2[3]) + (a3[0]+a3[1]+a3[2]+a3[3]);
  if (t < 9) sg[t] = 0.f;
  __syncthreads();
  bool special = (h < 2) || (h >= 62);
  int ridx = (h < 2) ? h : h - 60;
  float red = local;
  #pragma unroll
  for (int off = 32; off > 0; off >>= 1) red += __shfl_down(red, off, 64);
  if ((t & 63) == 0) atomicAdd(&sg[0], red);
  if (special) atomicAdd(&sg[1 + ridx], local);
  if (q == 0) {
    atomicAdd(&sg[5], a0[0]); atomicAdd(&sg[6], a0[1]);
    if (special) { cor[ridx][0] = a0[0]; cor[ridx][1] = a0[1]; }
  }
  if (q == 3) {
    atomicAdd(&sg[7], a3[2]); atomicAdd(&sg[8], a3[3]);
    if (special) { cor[ridx][2] = a3[2]; cor[ridx][3] = a3[3]; }
  }
  __syncthreads();
  if (t == 0) {
    const int EX[3][2] = {{2,3},{0,3},{0,1}};
    float T = sg[0];
    #pragma unroll
    for (int i = 0; i < 3; i++)
      #pragma unroll
      for (int j = 0; j < 3; j++) {
        float Re = sg[1 + EX[i][0]] + sg[1 + EX[i][1]];
        float Ce = sg[5 + EX[j][0]] + sg[5 + EX[j][1]];
        float Xc = cor[EX[i][0]][EX[j][0]] + cor[EX[i][0]][EX[j][1]]
                 + cor[EX[i][1]][EX[j][0]] + cor[EX[i][1]][EX[j][1]];
        sS[i * 3 + j] = T - Re - Ce + Xc;
      }
  }
  __syncthreads();
  if (t < EE) {
    const float* gw = gate_w + ((size_t)t * CC + c) * 9;
    float ge = 0.f;
    #pragma unroll
    for (int k = 0; k < 9; k++) ge += gw[k] * sS[k];
    int b = bc >> 6;
    gpart[b * (EE * CC) + t * CC + c] = ge;
  }
}

__global__ __launch_bounds__(256) void k_mix(
    const float* __restrict__ x, const float* __restrict__ expert_w,
    const float* __restrict__ gpart, const float* __restrict__ gate_b,
    float* __restrict__ out, float* __restrict__ ew_out) {
  __shared__ float gsh[EE];
  int t = threadIdx.x;
  int pt = blockIdx.x;
  int b  = blockIdx.y;
  {
    int e = t >> 5, j = t & 31;
    const float* gp = gpart + b * (EE * CC) + e * CC;
    float gval = gp[j] + gp[j + 32];
    #pragma unroll
    for (int off = 16; off > 0; off >>= 1) gval += __shfl_down(gval, off, 32);
    if (j == 0) gsh[e] = gval + 3844.0f * gate_b[e];
  }
  __syncthreads();
  float g[EE];
  #pragma unroll
  for (int e = 0; e < EE; e++) g[e] = gsh[e];
  int best = 0; float bg = g[0];
  #pragma unroll
  for (int e = 1; e < EE; e++) if (g[e] > bg) { bg = g[e]; best = e; }
  float s = 0.f;
  #pragma unroll
  for (int e = 0; e < EE; e++) s += __expf(g[e] - bg);
  float sc = 1.0f / s;
  if (pt == 0 && t < EE) ew_out[b * EE + t] = (t == best) ? sc : 0.f;
  int wave = t >> 6;
  int lane = t & 63;
  int l15  = lane & 15;
  int quad = lane >> 4;
  const float* Wg = expert_w + (size_t)best * (CC * CC);
  bf16x8 afr[4][2];
  #pragma unroll
  for (int ft = 0; ft < 4; ft++) {
    const float* wrow = Wg + (ft * 16 + l15) * CC + quad * 8;
    #pragma unroll
    for (int kk = 0; kk < 2; kk++) {
      f4 w0 = *(const f4*)(wrow + kk * 32);
      f4 w1 = *(const f4*)(wrow + kk * 32 + 4);
      frag_cast fc;
      fc.u[0] = pack2(w0[0], w0[1]); fc.u[1] = pack2(w0[2], w0[3]);
      fc.u[2] = pack2(w1[0], w1[1]); fc.u[3] = pack2(w1[2], w1[3]);
      afr[ft][kk] = fc.v;
    }
  }
  const float* Xb = x + (size_t)b * CC * HWX + pt * PXT + 32 * wave;
  f32x4 acc[2][4] = {};
  #pragma unroll
  for (int ss = 0; ss < 2; ss++) {
    const float* xp = Xb + ss * 16 + l15 + (size_t)(quad * 8) * HWX;
    #pragma unroll
    for (int kk = 0; kk < 2; kk++) {
      const float* xq = xp + (size_t)(kk * 32) * HWX;
      float e0 = xq[0], e1 = xq[HWX], e2 = xq[2*HWX], e3 = xq[3*HWX];
      float e4 = xq[4*HWX], e5 = xq[5*HWX], e6 = xq[6*HWX], e7 = xq[7*HWX];
      frag_cast fb;
      fb.u[0] = pack2(e0, e1); fb.u[1] = pack2(e2, e3);
      fb.u[2] = pack2(e4, e5); fb.u[3] = pack2(e6, e7);
      #pragma unroll
      for (int ft = 0; ft < 4; ft++)
        acc[ss][ft] = __builtin_amdgcn_mfma_f32_16x16x32_bf16(
            afr[ft][kk], fb.v, acc[ss][ft], 0, 0, 0);
    }
  }
  #pragma unroll
  for (int ss = 0; ss < 2; ss++) {
    #pragma unroll
    for (int ft = 0; ft < 4; ft++) {
      int f = ft * 16 + quad * 4;
      float* Og = out + ((size_t)(b * CC + f)) * HWX
                + pt * PXT + 32 * wave + ss * 16 + l15;
      #pragma unroll
      for (int r = 0; r < 4; r++)
        Og[(size_t)r * HWX] = sc * acc[ss][ft][r];
    }
  }
}

// ---------------------------------------------------------------------------
extern "C" void kernel_launch(void* const* d_in, const int* in_sizes, int n_in,
                              void* d_out, int out_size, void* d_ws, size_t ws_size,
                              hipStream_t stream) {
  const float* x        = (const float*)d_in[0];   // [32,64,64,64]
  const float* gate_w   = (const float*)d_in[1];   // [8,64,3,3]
  const float* gate_b   = (const float*)d_in[2];   // [8]
  const float* expert_w = (const float*)d_in[3];   // [8,64,64]
  float* out = (float*)d_out;                      // [32,64,64,64] then [32,8]
  float* ew_out = out + (size_t)BB * CC * HWX;

  float* gcontrib = (float*)d_ws;                  // [32][32][8], fully written
  float* gpart    = (float*)d_ws + 16384;          // fallback region

  void* args[] = {(void*)&x, (void*)&gate_w, (void*)&gate_b, (void*)&expert_w,
                  (void*)&out, (void*)&ew_out, (void*)&gcontrib};
  hipError_t err = hipLaunchCooperativeKernel(
      (const void*)k_fused, dim3(BB * 32), dim3(256), args, 0, stream);
  if (err != hipSuccess) {
    // fallback: verified two-kernel path
    k_gate_sums<<<BB * CC, 256, 0, stream>>>(x, gate_w, gpart);
    k_mix<<<dim3(HWX / PXT, BB), 256, 0, stream>>>(x, expert_w, gpart, gate_b,
                                                   out, ew_out);
  }
}

// Round 5
// 100.824 us; speedup vs baseline: 1.7733x; 1.7733x over previous
//
#include <hip/hip_runtime.h>

typedef float f4 __attribute__((ext_vector_type(4)));
typedef short bf16x8 __attribute__((ext_vector_type(8)));
typedef float f32x4 __attribute__((ext_vector_type(4)));

#define BB 32
#define CC 64
#define EE 8
#define HWX 4096   // 64*64 pixels
#define PXT 128    // pixels per mix block

// ---------------------------------------------------------------------------
// bf16 round-to-nearest-even helpers
// ---------------------------------------------------------------------------
__device__ __forceinline__ unsigned bf16r(float f) {
  unsigned u = __builtin_bit_cast(unsigned, f);
  u += 0x7FFFu + ((u >> 16) & 1u);
  return u >> 16;
}
__device__ __forceinline__ unsigned pack2(float a, float b) {
  return bf16r(a) | (bf16r(b) << 16);
}
union frag_cast { bf16x8 v; unsigned u[4]; };

// ---------------------------------------------------------------------------
// Kernel A: per-(b,c) plane reductions -> per-c gating partials (no atomics
// to global; LDS atomics minimized via wave-level shuffle reductions).
// gpart[b][e][c] = sum_{i,j} gw[e,c,i,j] * S[b,c,i,j]
// S[i,j] = T - excludedRows(i) - excludedCols(j) + corners(i,j)
// ---------------------------------------------------------------------------
__global__ __launch_bounds__(256) void k_gate_sums(
    const float* __restrict__ x, const float* __restrict__ gate_w,
    float* __restrict__ gpart) {
  __shared__ float sg[9];       // [T, r0,r1,r62,r63, c0,c1,c62,c63]
  __shared__ float cor[4][4];   // corner cells, rows/cols in {0,1,62,63}
  __shared__ float sS[9];       // the 9 window sums S[i*3+j]
  int t = threadIdx.x;
  int bc = blockIdx.x;          // b*64 + c
  int c = bc & 63;
  const float* plane = x + (size_t)bc * HWX;
  int h = t >> 2, q = t & 3;    // row h (0..63), quarter q (16 floats each)
  const f4* rp = (const f4*)(plane + h * 64 + q * 16);
  f4 a0 = rp[0], a1 = rp[1], a2 = rp[2], a3 = rp[3];
  float local = (a0[0]+a0[1]+a0[2]+a0[3]) + (a1[0]+a1[1]+a1[2]+a1[3])
              + (a2[0]+a2[1]+a2[2]+a2[3]) + (a3[0]+a3[1]+a3[2]+a3[3]);
  if (t < 9) sg[t] = 0.f;
  __syncthreads();

  bool special = (h < 2) || (h >= 62);
  int ridx = (h < 2) ? h : h - 60;   // 0,1,62,63 -> 0,1,2,3

  // ---- wave-level reductions: total + 4 column sums, 5 atomics per wave ----
  float red = local;
  float c0v = (q == 0) ? a0[0] : 0.f;   // col 0
  float c1v = (q == 0) ? a0[1] : 0.f;   // col 1
  float c2v = (q == 3) ? a3[2] : 0.f;   // col 62
  float c3v = (q == 3) ? a3[3] : 0.f;   // col 63
  #pragma unroll
  for (int off = 32; off > 0; off >>= 1) {
    red += __shfl_down(red, off, 64);
    c0v += __shfl_down(c0v, off, 64);
    c1v += __shfl_down(c1v, off, 64);
    c2v += __shfl_down(c2v, off, 64);
    c3v += __shfl_down(c3v, off, 64);
  }
  if ((t & 63) == 0) {
    atomicAdd(&sg[0], red);
    atomicAdd(&sg[5], c0v); atomicAdd(&sg[6], c1v);
    atomicAdd(&sg[7], c2v); atomicAdd(&sg[8], c3v);
  }

  if (special) {
    atomicAdd(&sg[1 + ridx], local);                     // full-row sums (4/addr)
    if (q == 0) { cor[ridx][0] = a0[0]; cor[ridx][1] = a0[1]; }
    if (q == 3) { cor[ridx][2] = a3[2]; cor[ridx][3] = a3[3]; }
  }
  __syncthreads();

  if (t == 0) {
    const int EX[3][2] = {{2,3},{0,3},{0,1}};  // excluded indices per offset
    float T = sg[0];
    #pragma unroll
    for (int i = 0; i < 3; i++)
      #pragma unroll
      for (int j = 0; j < 3; j++) {
        float Re = sg[1 + EX[i][0]] + sg[1 + EX[i][1]];
        float Ce = sg[5 + EX[j][0]] + sg[5 + EX[j][1]];
        float Xc = cor[EX[i][0]][EX[j][0]] + cor[EX[i][0]][EX[j][1]]
                 + cor[EX[i][1]][EX[j][0]] + cor[EX[i][1]][EX[j][1]];
        sS[i * 3 + j] = T - Re - Ce + Xc;
      }
  }
  __syncthreads();

  if (t < EE) {
    const float* gw = gate_w + ((size_t)t * CC + c) * 9;
    float ge = 0.f;
    #pragma unroll
    for (int k = 0; k < 9; k++) ge += gw[k] * sS[k];
    int b = bc >> 6;
    gpart[b * (EE * CC) + t * CC + c] = ge;   // direct store, no atomic
  }
}

// ---------------------------------------------------------------------------
// Kernel B: gating reduce + softmax/top-1 + MFMA expert 1x1-conv mix.
// Block: (pt, b) = one batch, 128 px. 4 waves; wave w owns px [32w, 32w+32).
// x-loads hoisted to the top so their latency overlaps the gating reduce.
// MFMA layouts (HW-verified m89/m91/m120):
//   A[m=lane&15][k=quad*8+j], B[k=quad*8+j][n=lane&15],
//   D: col(n)=lane&15, row(m)=quad*4+reg.
// ---------------------------------------------------------------------------
__global__ __launch_bounds__(256) void k_mix(
    const float* __restrict__ x, const float* __restrict__ expert_w,
    const float* __restrict__ gpart, const float* __restrict__ gate_b,
    float* __restrict__ out, float* __restrict__ ew_out) {
  __shared__ float gsh[EE];
  int t = threadIdx.x;
  int pt = blockIdx.x;            // 0..31 pixel tile (128 px)
  int b  = blockIdx.y;
  int wave = t >> 6;
  int lane = t & 63;
  int l15  = lane & 15;
  int quad = lane >> 4;

  // ---- hoisted B-operand loads (independent of gating result) ----
  const float* Xb = x + (size_t)b * CC * HWX + pt * PXT + 32 * wave;
  float xv[2][2][8];              // [ss][kk][j]; channel = kk*32 + quad*8 + j
  #pragma unroll
  for (int ss = 0; ss < 2; ss++) {
    const float* xp = Xb + ss * 16 + l15 + (size_t)(quad * 8) * HWX;
    #pragma unroll
    for (int kk = 0; kk < 2; kk++) {
      const float* xq = xp + (size_t)(kk * 32) * HWX;
      #pragma unroll
      for (int j = 0; j < 8; j++) xv[ss][kk][j] = xq[(size_t)j * HWX];
    }
  }

  // ---- gating reduction: 8 experts x 32 lanes ----
  {
    int e = t >> 5, j = t & 31;
    const float* gp = gpart + b * (EE * CC) + e * CC;
    float gval = gp[j] + gp[j + 32];
    #pragma unroll
    for (int off = 16; off > 0; off >>= 1) gval += __shfl_down(gval, off, 32);
    if (j == 0) gsh[e] = gval + 3844.0f * gate_b[e];
  }
  __syncthreads();

  // ---- every thread: top-1 softmax (block-uniform result) ----
  float g[EE];
  #pragma unroll
  for (int e = 0; e < EE; e++) g[e] = gsh[e];
  int best = 0; float bg = g[0];
  #pragma unroll
  for (int e = 1; e < EE; e++) if (g[e] > bg) { bg = g[e]; best = e; }
  float s = 0.f;
  #pragma unroll
  for (int e = 0; e < EE; e++) s += __expf(g[e] - bg);
  float sc = 1.0f / s;            // top-1 softmax prob
  if (pt == 0 && t < EE) ew_out[b * EE + t] = (t == best) ? sc : 0.f;

  // ---- A-frags: W[best][f0+l15][k0+quad*8+j], 4 f-tiles x 2 k0 ----
  const float* Wg = expert_w + (size_t)best * (CC * CC);
  bf16x8 afr[4][2];
  #pragma unroll
  for (int ft = 0; ft < 4; ft++) {
    const float* wrow = Wg + (ft * 16 + l15) * CC + quad * 8;
    #pragma unroll
    for (int kk = 0; kk < 2; kk++) {
      f4 w0 = *(const f4*)(wrow + kk * 32);
      f4 w1 = *(const f4*)(wrow + kk * 32 + 4);
      frag_cast fc;
      fc.u[0] = pack2(w0[0], w0[1]); fc.u[1] = pack2(w0[2], w0[3]);
      fc.u[2] = pack2(w1[0], w1[1]); fc.u[3] = pack2(w1[2], w1[3]);
      afr[ft][kk] = fc.v;
    }
  }

  // ---- pack B-frags + MFMA ----
  f32x4 acc[2][4] = {};           // [ss][ft]
  #pragma unroll
  for (int ss = 0; ss < 2; ss++) {
    #pragma unroll
    for (int kk = 0; kk < 2; kk++) {
      frag_cast fb;
      fb.u[0] = pack2(xv[ss][kk][0], xv[ss][kk][1]);
      fb.u[1] = pack2(xv[ss][kk][2], xv[ss][kk][3]);
      fb.u[2] = pack2(xv[ss][kk][4], xv[ss][kk][5]);
      fb.u[3] = pack2(xv[ss][kk][6], xv[ss][kk][7]);
      #pragma unroll
      for (int ft = 0; ft < 4; ft++)
        acc[ss][ft] = __builtin_amdgcn_mfma_f32_16x16x32_bf16(
            afr[ft][kk], fb.v, acc[ss][ft], 0, 0, 0);
    }
  }

  // ---- scaled store: f = 16*ft + quad*4 + r, px = pt*128+32w+16s+l15 ----
  #pragma unroll
  for (int ss = 0; ss < 2; ss++) {
    #pragma unroll
    for (int ft = 0; ft < 4; ft++) {
      int f = ft * 16 + quad * 4;
      float* Og = out + ((size_t)(b * CC + f)) * HWX
                + pt * PXT + 32 * wave + ss * 16 + l15;
      #pragma unroll
      for (int r = 0; r < 4; r++)
        Og[(size_t)r * HWX] = sc * acc[ss][ft][r];
    }
  }
}

// ---------------------------------------------------------------------------
extern "C" void kernel_launch(void* const* d_in, const int* in_sizes, int n_in,
                              void* d_out, int out_size, void* d_ws, size_t ws_size,
                              hipStream_t stream) {
  const float* x        = (const float*)d_in[0];   // [32,64,64,64]
  const float* gate_w   = (const float*)d_in[1];   // [8,64,3,3]
  const float* gate_b   = (const float*)d_in[2];   // [8]
  const float* expert_w = (const float*)d_in[3];   // [8,64,64]
  float* out = (float*)d_out;                      // [32,64,64,64] then [32,8]
  float* ew_out = out + (size_t)BB * CC * HWX;

  float* gpart = (float*)d_ws;   // [32][8][64] partials, fully written by kA

  k_gate_sums<<<BB * CC, 256, 0, stream>>>(x, gate_w, gpart);
  k_mix<<<dim3(HWX / PXT, BB), 256, 0, stream>>>(x, expert_w, gpart, gate_b,
                                                 out, ew_out);
}